// Round 1
// baseline (461.510 us; speedup 1.0000x reference)
//
#include <hip/hip_runtime.h>
#include <stdint.h>

// ---------------------------------------------------------------------------
// Problem constants (from reference)
// ---------------------------------------------------------------------------
#define N_PIX   32768      // B*H*W = 8*64*64
#define C_DIM   512
#define K_Q     3072
#define NCLS    4
#define NQ      256
#define N_SAMP  1024       // NCLS*NQ
#define HW      4096       // H*W
#define L_ROW   3073       // 1 + K_Q

// RNG scheme: 1 = partitionable threefry (modern JAX default),
//             0 = original iota-split threefry (older JAX)
#define SCHEME 1

// ---------------------------------------------------------------------------
// Threefry2x32-20 (matches jax/_src/prng.py lowering exactly)
// ---------------------------------------------------------------------------
__host__ __device__ inline void tf2x32(uint32_t k0, uint32_t k1,
                                       uint32_t x0, uint32_t x1,
                                       uint32_t& o0, uint32_t& o1) {
  uint32_t ks2 = k0 ^ k1 ^ 0x1BD11BDAu;
  x0 += k0; x1 += k1;
#define ROTL_(v,d) (((v)<<(d))|((v)>>(32-(d))))
#define RND_(r) { x0 += x1; x1 = ROTL_(x1, r); x1 ^= x0; }
  RND_(13) RND_(15) RND_(26) RND_(6)
  x0 += k1; x1 += ks2 + 1u;
  RND_(17) RND_(29) RND_(16) RND_(24)
  x0 += ks2; x1 += k0 + 2u;
  RND_(13) RND_(15) RND_(26) RND_(6)
  x0 += k0; x1 += k1 + 3u;
  RND_(17) RND_(29) RND_(16) RND_(24)
  x0 += k1; x1 += ks2 + 4u;
  RND_(13) RND_(15) RND_(26) RND_(6)
  x0 += ks2; x1 += k0 + 5u;
  o0 = x0; o1 = x1;
#undef RND_
#undef ROTL_
}

// ---------------------------------------------------------------------------
// K0: zero per-class counters
// ---------------------------------------------------------------------------
__global__ void k_zero(int* cnt) {
  if (threadIdx.x < NCLS) cnt[threadIdx.x] = 0;
}

// ---------------------------------------------------------------------------
// K1: compact valid-pixel lists per class (order irrelevant: max-reduce later)
// ---------------------------------------------------------------------------
__global__ __launch_bounds__(256) void k_compact(const int* __restrict__ target,
                                                 int* __restrict__ cnt,
                                                 int* __restrict__ lists) {
  int p = blockIdx.x * 256 + threadIdx.x;   // grid covers exactly N_PIX
  int c = target[p];
  int pos = atomicAdd(&cnt[c], 1);
  lists[c * N_PIX + pos] = p;
}

// ---------------------------------------------------------------------------
// K2: Gumbel-max sampling == argmax over valid pixels of raw uniform bits.
// One block per (class, draw). Pack (bits>>9, 32767-p) so max => max bits,
// tie => min p (matches jnp.argmax first-occurrence).
// ---------------------------------------------------------------------------
__global__ __launch_bounds__(256) void k_sample(
    const int* __restrict__ cnt, const int* __restrict__ lists,
    int* __restrict__ samp,
    uint32_t k0a, uint32_t k0b, uint32_t k1a, uint32_t k1b,
    uint32_t k2a, uint32_t k2b, uint32_t k3a, uint32_t k3b) {
  int c = blockIdx.y;
  int q = blockIdx.x;
  uint32_t ka, kb;
  if      (c == 0) { ka = k0a; kb = k0b; }
  else if (c == 1) { ka = k1a; kb = k1b; }
  else if (c == 2) { ka = k2a; kb = k2b; }
  else             { ka = k3a; kb = k3b; }

  int nv = cnt[c];
  const int* lst = lists + c * N_PIX;
  unsigned long long best = 0ull;
  for (int t = threadIdx.x; t < nv; t += 256) {
    int p = lst[t];
    uint32_t j = (uint32_t)(q * N_PIX + p);   // flat element index (q, p)
    uint32_t o0, o1, bits;
#if SCHEME
    tf2x32(ka, kb, 0u, j, o0, o1);
    bits = o0 ^ o1;
#else
    const uint32_t HALF = (uint32_t)(NQ / 2) * N_PIX;  // 4194304
    if (j < HALF) { tf2x32(ka, kb, j, j + HALF, o0, o1); bits = o0; }
    else          { tf2x32(ka, kb, j - HALF, j, o0, o1); bits = o1; }
#endif
    unsigned long long v =
        ((unsigned long long)(bits >> 9) << 15) | (unsigned)(32767 - p);
    if (v > best) best = v;
  }
  __shared__ unsigned long long red[256];
  red[threadIdx.x] = best;
  __syncthreads();
  for (int s = 128; s > 0; s >>= 1) {
    if (threadIdx.x < s && red[threadIdx.x + s] > red[threadIdx.x])
      red[threadIdx.x] = red[threadIdx.x + s];
    __syncthreads();
  }
  if (threadIdx.x == 0)
    samp[c * NQ + q] = 32767 - (int)(red[0] & 0x7FFFull);
}

// ---------------------------------------------------------------------------
// K3: shuffle = stable sort of arange(1024) by random u32 keys (1 round).
// O(n^2) rank in one block. Writes final gather indices, labels (ws + out).
// ---------------------------------------------------------------------------
__global__ __launch_bounds__(1024) void k_perm(
    const int* __restrict__ samp, int* __restrict__ idx_final,
    int* __restrict__ labels_shuf, float* __restrict__ out_labels,
    uint32_t sk0, uint32_t sk1) {
  __shared__ uint32_t keys_s[N_SAMP];
  int i = threadIdx.x;
  uint32_t o0, o1;
#if SCHEME
  tf2x32(sk0, sk1, 0u, (uint32_t)i, o0, o1);
  keys_s[i] = o0 ^ o1;
#else
  if (i < 512) { tf2x32(sk0, sk1, (uint32_t)i, (uint32_t)(i + 512), o0, o1); keys_s[i] = o0; }
  else         { tf2x32(sk0, sk1, (uint32_t)(i - 512), (uint32_t)i, o0, o1); keys_s[i] = o1; }
#endif
  __syncthreads();
  uint32_t ki = keys_s[i];
  int rank = 0;
  for (int j = 0; j < N_SAMP; ++j) {
    uint32_t kj = keys_s[j];
    rank += (kj < ki) || (kj == ki && j < i);
  }
  // sorted position `rank` holds original index i
  idx_final[rank] = samp[i];
  int lab = i >> 8;                  // labels = repeat(arange(4), 256)
  labels_shuf[rank] = lab;
  out_labels[rank] = (float)lab;
}

// ---------------------------------------------------------------------------
// K4: gather sampled rows, L2-normalize (only the 1024 needed rows),
// store normalized student feats for GEMM, write l_pos (logits col 0).
// ---------------------------------------------------------------------------
__global__ __launch_bounds__(256) void k_gather(
    const float* __restrict__ fs, const float* __restrict__ ft,
    const int* __restrict__ idx_final, float* __restrict__ feats,
    float* __restrict__ out_logits) {
  int n = blockIdx.x;
  int p = idx_final[n];
  int b = p >> 12;
  int hw = p & (HW - 1);
  const float* fsb = fs + (size_t)b * C_DIM * HW + hw;
  const float* ftb = ft + (size_t)b * C_DIM * HW + hw;
  int c0 = threadIdx.x, c1 = threadIdx.x + 256;
  float s0 = fsb[(size_t)c0 * HW], s1 = fsb[(size_t)c1 * HW];
  float t0 = ftb[(size_t)c0 * HW], t1 = ftb[(size_t)c1 * HW];

  __shared__ float red[256];
  __shared__ float ns_sh, nt_sh;

  red[threadIdx.x] = s0 * s0 + s1 * s1;
  __syncthreads();
  for (int s = 128; s > 0; s >>= 1) {
    if (threadIdx.x < s) red[threadIdx.x] += red[threadIdx.x + s];
    __syncthreads();
  }
  if (threadIdx.x == 0) ns_sh = fmaxf(sqrtf(red[0]), 1e-12f);
  __syncthreads();

  red[threadIdx.x] = t0 * t0 + t1 * t1;
  __syncthreads();
  for (int s = 128; s > 0; s >>= 1) {
    if (threadIdx.x < s) red[threadIdx.x] += red[threadIdx.x + s];
    __syncthreads();
  }
  if (threadIdx.x == 0) nt_sh = fmaxf(sqrtf(red[0]), 1e-12f);
  __syncthreads();

  float ns = ns_sh, nt = nt_sh;
  float a0 = s0 / ns, a1 = s1 / ns;
  float b0 = t0 / nt, b1 = t1 / nt;
  feats[(size_t)n * C_DIM + c0] = a0;
  feats[(size_t)n * C_DIM + c1] = a1;

  red[threadIdx.x] = a0 * b0 + a1 * b1;
  __syncthreads();
  for (int s = 128; s > 0; s >>= 1) {
    if (threadIdx.x < s) red[threadIdx.x] += red[threadIdx.x + s];
    __syncthreads();
  }
  if (threadIdx.x == 0)
    out_logits[(size_t)n * L_ROW] = red[0] / 0.07f;   // l_pos / temperature
}

// ---------------------------------------------------------------------------
// K5: l_neg = feats(1024x512) @ queue(512x3072), f32 VALU GEMM, 64x64x32
// tiles, 4x4 register micro-tile per thread. Mask fused in epilogue.
// ---------------------------------------------------------------------------
#define BM 64
#define BN 64
#define BK 32
__global__ __launch_bounds__(256) void k_gemm(
    const float* __restrict__ A,    // feats [N_SAMP][C_DIM]
    const float* __restrict__ Bq,   // queue [C_DIM][K_Q]
    const int* __restrict__ labels, // shuffled labels [N_SAMP]
    const int* __restrict__ qlab,   // queue_labels [K_Q]
    float* __restrict__ out) {
  __shared__ float As[BK][BM];
  __shared__ float Bs[BK][BN];
  int bm = blockIdx.x * BM;
  int bn = blockIdx.y * BN;
  int tid = threadIdx.x;
  int tx = tid & 15, ty = tid >> 4;

  float acc[4][4] = {};
  for (int k0 = 0; k0 < C_DIM; k0 += BK) {
    // stage A: 64 rows x 32 k (transposed into As[k][m])
#pragma unroll
    for (int it = 0; it < 2; ++it) {
      int lin = tid + it * 256;        // 0..511
      int r = lin >> 3;                // 0..63
      int g = lin & 7;                 // 0..7 (float4 group in k)
      float4 v = *(const float4*)(A + (size_t)(bm + r) * C_DIM + k0 + g * 4);
      As[g * 4 + 0][r] = v.x; As[g * 4 + 1][r] = v.y;
      As[g * 4 + 2][r] = v.z; As[g * 4 + 3][r] = v.w;
    }
    // stage B: 32 k x 64 cols
#pragma unroll
    for (int it = 0; it < 2; ++it) {
      int lin = tid + it * 256;
      int kr = lin >> 4;               // 0..31
      int g = lin & 15;                // 0..15
      float4 v = *(const float4*)(Bq + (size_t)(k0 + kr) * K_Q + bn + g * 4);
      *(float4*)&Bs[kr][g * 4] = v;
    }
    __syncthreads();
#pragma unroll
    for (int k = 0; k < BK; ++k) {
      float a4[4], b4[4];
      *(float4*)a4 = *(const float4*)&As[k][ty * 4];
      *(float4*)b4 = *(const float4*)&Bs[k][tx * 4];
#pragma unroll
      for (int i = 0; i < 4; ++i)
#pragma unroll
        for (int j = 0; j < 4; ++j)
          acc[i][j] = fmaf(a4[i], b4[j], acc[i][j]);
    }
    __syncthreads();
  }

  float* out_mask = out + (size_t)N_SAMP * L_ROW;
#pragma unroll
  for (int i = 0; i < 4; ++i) {
    int row = bm + ty * 4 + i;
    int lab = labels[row];
    float* lrow = out + (size_t)row * L_ROW + 1 + bn + tx * 4;
    float* mrow = out_mask + (size_t)row * K_Q + bn + tx * 4;
#pragma unroll
    for (int j = 0; j < 4; ++j) {
      lrow[j] = acc[i][j] / 0.07f;
      mrow[j] = (lab == qlab[bn + tx * 4 + j]) ? 1.0f : 0.0f;
    }
  }
}

// ---------------------------------------------------------------------------
// Launch
// ---------------------------------------------------------------------------
extern "C" void kernel_launch(void* const* d_in, const int* in_sizes, int n_in,
                              void* d_out, int out_size, void* d_ws, size_t ws_size,
                              hipStream_t stream) {
  const float* fs     = (const float*)d_in[1];
  const float* ft     = (const float*)d_in[2];
  const int*   target = (const int*)d_in[3];
  const float* queue  = (const float*)d_in[4];
  const int*   qlab   = (const int*)d_in[5];
  float* out = (float*)d_out;

  // ws layout (all 256B-aligned)
  char* ws = (char*)d_ws;
  int*   cnt    = (int*)(ws + 0);
  int*   samp   = (int*)(ws + 256);
  int*   idxf   = (int*)(ws + 256 + 4096);
  int*   labs   = (int*)(ws + 256 + 8192);
  int*   lists  = (int*)(ws + 256 + 12288);                 // 4*32768*4 B
  float* feats  = (float*)(ws + 256 + 12288 + 4 * N_PIX * 4);

  // --- host-side RNG key derivation (pure CPU math; identical every call) ---
  uint32_t ck[5][2];
#if SCHEME
  // fold-like split: keys[i] = TF(key, hi=0, lo=i)
  for (int i = 0; i < 5; ++i)
    tf2x32(0u, 42u, 0u, (uint32_t)i, ck[i][0], ck[i][1]);
  // subkey = split(keys[4], 2)[1] = TF(keys[4], 0, 1)
  uint32_t sk0, sk1;
  tf2x32(ck[4][0], ck[4][1], 0u, 1u, sk0, sk1);
#else
  // original split: counts iota(10), x0=[0..4], x1=[5..9]
  uint32_t a[5], b[5];
  for (int i = 0; i < 5; ++i)
    tf2x32(0u, 42u, (uint32_t)i, (uint32_t)(i + 5), a[i], b[i]);
  ck[0][0] = a[0]; ck[0][1] = a[1];
  ck[1][0] = a[2]; ck[1][1] = a[3];
  ck[2][0] = a[4]; ck[2][1] = b[0];
  ck[3][0] = b[1]; ck[3][1] = b[2];
  ck[4][0] = b[3]; ck[4][1] = b[4];
  // subkey = split(keys[4], 2)[1]: counts iota(4), pairs (0,2),(1,3); row1 = lane1s
  uint32_t c0_, d0_, c1_, d1_;
  tf2x32(ck[4][0], ck[4][1], 0u, 2u, c0_, d0_);
  tf2x32(ck[4][0], ck[4][1], 1u, 3u, c1_, d1_);
  uint32_t sk0 = d0_, sk1 = d1_;
#endif

  float* out_labels = out + (size_t)N_SAMP * L_ROW + (size_t)N_SAMP * K_Q;

  k_zero<<<1, 64, 0, stream>>>(cnt);
  k_compact<<<N_PIX / 256, 256, 0, stream>>>(target, cnt, lists);
  k_sample<<<dim3(NQ, NCLS), 256, 0, stream>>>(
      cnt, lists, samp,
      ck[0][0], ck[0][1], ck[1][0], ck[1][1],
      ck[2][0], ck[2][1], ck[3][0], ck[3][1]);
  k_perm<<<1, 1024, 0, stream>>>(samp, idxf, labs, out_labels, sk0, sk1);
  k_gather<<<N_SAMP, 256, 0, stream>>>(fs, ft, idxf, feats, out);
  k_gemm<<<dim3(N_SAMP / BM, K_Q / BN), 256, 0, stream>>>(
      feats, queue, labs, qlab, out);
}

// Round 3
// 277.996 us; speedup vs baseline: 1.6601x; 1.6601x over previous
//
#include <hip/hip_runtime.h>
#include <stdint.h>

// ---------------------------------------------------------------------------
// Problem constants (from reference)
// ---------------------------------------------------------------------------
#define N_PIX   32768      // B*H*W = 8*64*64
#define C_DIM   512
#define K_Q     3072
#define NCLS    4
#define NQ      256
#define N_SAMP  1024       // NCLS*NQ
#define HW      4096       // H*W
#define L_ROW   3073       // 1 + K_Q

// RNG scheme: 1 = partitionable threefry (modern JAX default) — VERIFIED R1
#define SCHEME 1

// ---------------------------------------------------------------------------
// Threefry2x32-20 (matches jax/_src/prng.py lowering exactly)
// ---------------------------------------------------------------------------
__host__ __device__ inline void tf2x32(uint32_t k0, uint32_t k1,
                                       uint32_t x0, uint32_t x1,
                                       uint32_t& o0, uint32_t& o1) {
  uint32_t ks2 = k0 ^ k1 ^ 0x1BD11BDAu;
  x0 += k0; x1 += k1;
#define ROTL_(v,d) (((v)<<(d))|((v)>>(32-(d))))
#define RND_(r) { x0 += x1; x1 = ROTL_(x1, r); x1 ^= x0; }
  RND_(13) RND_(15) RND_(26) RND_(6)
  x0 += k1; x1 += ks2 + 1u;
  RND_(17) RND_(29) RND_(16) RND_(24)
  x0 += ks2; x1 += k0 + 2u;
  RND_(13) RND_(15) RND_(26) RND_(6)
  x0 += k0; x1 += k1 + 3u;
  RND_(17) RND_(29) RND_(16) RND_(24)
  x0 += k1; x1 += ks2 + 4u;
  RND_(13) RND_(15) RND_(26) RND_(6)
  x0 += ks2; x1 += k0 + 5u;
  o0 = x0; o1 = x1;
#undef RND_
#undef ROTL_
}

// ---------------------------------------------------------------------------
// K0: zero per-class counters
// ---------------------------------------------------------------------------
__global__ void k_zero(int* cnt) {
  if (threadIdx.x < NCLS) cnt[threadIdx.x] = 0;
}

// ---------------------------------------------------------------------------
// K1: compact valid-pixel lists per class.
// R1 post-mortem: per-thread global atomics on 4 addresses = 178 us (atomic
// serialization, ~200cy x 32768). Fix: LDS histogram per block, then ONE
// global atomicAdd per class per block (512 total). List order changes but
// k_sample's argmax packs p into the comparator -> order-invariant.
// ---------------------------------------------------------------------------
__global__ __launch_bounds__(256) void k_compact(const int* __restrict__ target,
                                                 int* __restrict__ cnt,
                                                 int* __restrict__ lists) {
  __shared__ int lcnt[NCLS];
  __shared__ int lbase[NCLS];
  int tid = threadIdx.x;
  if (tid < NCLS) lcnt[tid] = 0;
  __syncthreads();
  int p = blockIdx.x * 256 + tid;   // grid covers exactly N_PIX
  int c = target[p];
  int lpos = atomicAdd(&lcnt[c], 1);          // LDS atomic (4 banks)
  __syncthreads();
  if (tid < NCLS) lbase[tid] = atomicAdd(&cnt[tid], lcnt[tid]);  // 4 global/block
  __syncthreads();
  lists[c * N_PIX + lbase[c] + lpos] = p;
}

// ---------------------------------------------------------------------------
// K2: Gumbel-max sampling == argmax over valid pixels of raw uniform bits.
// One block per (class, draw). Pack (bits>>9, 32767-p) so max => max bits,
// tie => min p (matches jnp.argmax first-occurrence).
// ---------------------------------------------------------------------------
__global__ __launch_bounds__(256) void k_sample(
    const int* __restrict__ cnt, const int* __restrict__ lists,
    int* __restrict__ samp,
    uint32_t k0a, uint32_t k0b, uint32_t k1a, uint32_t k1b,
    uint32_t k2a, uint32_t k2b, uint32_t k3a, uint32_t k3b) {
  int c = blockIdx.y;
  int q = blockIdx.x;
  uint32_t ka, kb;
  if      (c == 0) { ka = k0a; kb = k0b; }
  else if (c == 1) { ka = k1a; kb = k1b; }
  else if (c == 2) { ka = k2a; kb = k2b; }
  else             { ka = k3a; kb = k3b; }

  int nv = cnt[c];
  const int* lst = lists + c * N_PIX;
  unsigned long long best = 0ull;
  for (int t = threadIdx.x; t < nv; t += 256) {
    int p = lst[t];
    uint32_t j = (uint32_t)(q * N_PIX + p);   // flat element index (q, p)
    uint32_t o0, o1, bits;
    tf2x32(ka, kb, 0u, j, o0, o1);
    bits = o0 ^ o1;
    unsigned long long v =
        ((unsigned long long)(bits >> 9) << 15) | (unsigned)(32767 - p);
    if (v > best) best = v;
  }
  __shared__ unsigned long long red[256];
  red[threadIdx.x] = best;
  __syncthreads();
  for (int s = 128; s > 0; s >>= 1) {
    if (threadIdx.x < s && red[threadIdx.x + s] > red[threadIdx.x])
      red[threadIdx.x] = red[threadIdx.x + s];
    __syncthreads();
  }
  if (threadIdx.x == 0)
    samp[c * NQ + q] = 32767 - (int)(red[0] & 0x7FFFull);
}

// ---------------------------------------------------------------------------
// K3: shuffle = stable sort of arange(1024) by random u32 keys (1 round).
// R1: single 1024-thread block = 1 CU, ~23 us estimated. Now 16 blocks x 64
// threads; each block redundantly recomputes the 1024 keys (16 tf/thread,
// cheap) into LDS, then ranks its 64-element slice.
// ---------------------------------------------------------------------------
__global__ __launch_bounds__(64) void k_perm(
    const int* __restrict__ samp, int* __restrict__ idx_final,
    int* __restrict__ labels_shuf, float* __restrict__ out_labels,
    uint32_t sk0, uint32_t sk1) {
  __shared__ uint32_t keys_s[N_SAMP];
  int lt = threadIdx.x;  // 0..63
  for (int t = lt; t < N_SAMP; t += 64) {
    uint32_t o0, o1;
    tf2x32(sk0, sk1, 0u, (uint32_t)t, o0, o1);
    keys_s[t] = o0 ^ o1;
  }
  __syncthreads();
  int i = blockIdx.x * 64 + lt;
  uint32_t ki = keys_s[i];
  int rank = 0;
#pragma unroll 4
  for (int j = 0; j < N_SAMP; ++j) {
    uint32_t kj = keys_s[j];
    rank += (int)((kj < ki) | ((kj == ki) & (j < i)));
  }
  // sorted position `rank` holds original index i
  idx_final[rank] = samp[i];
  int lab = i >> 8;                  // labels = repeat(arange(4), 256)
  labels_shuf[rank] = lab;
  out_labels[rank] = (float)lab;
}

// ---------------------------------------------------------------------------
// K4: gather sampled rows, L2-normalize (only the 1024 needed rows),
// store normalized student feats for GEMM, write l_pos (logits col 0).
// ---------------------------------------------------------------------------
__global__ __launch_bounds__(256) void k_gather(
    const float* __restrict__ fs, const float* __restrict__ ft,
    const int* __restrict__ idx_final, float* __restrict__ feats,
    float* __restrict__ out_logits) {
  int n = blockIdx.x;
  int p = idx_final[n];
  int b = p >> 12;
  int hw = p & (HW - 1);
  const float* fsb = fs + (size_t)b * C_DIM * HW + hw;
  const float* ftb = ft + (size_t)b * C_DIM * HW + hw;
  int c0 = threadIdx.x, c1 = threadIdx.x + 256;
  float s0 = fsb[(size_t)c0 * HW], s1 = fsb[(size_t)c1 * HW];
  float t0 = ftb[(size_t)c0 * HW], t1 = ftb[(size_t)c1 * HW];

  __shared__ float red[256];
  __shared__ float ns_sh, nt_sh;

  red[threadIdx.x] = s0 * s0 + s1 * s1;
  __syncthreads();
  for (int s = 128; s > 0; s >>= 1) {
    if (threadIdx.x < s) red[threadIdx.x] += red[threadIdx.x + s];
    __syncthreads();
  }
  if (threadIdx.x == 0) ns_sh = fmaxf(sqrtf(red[0]), 1e-12f);
  __syncthreads();

  red[threadIdx.x] = t0 * t0 + t1 * t1;
  __syncthreads();
  for (int s = 128; s > 0; s >>= 1) {
    if (threadIdx.x < s) red[threadIdx.x] += red[threadIdx.x + s];
    __syncthreads();
  }
  if (threadIdx.x == 0) nt_sh = fmaxf(sqrtf(red[0]), 1e-12f);
  __syncthreads();

  float ns = ns_sh, nt = nt_sh;
  float a0 = s0 / ns, a1 = s1 / ns;
  float b0 = t0 / nt, b1 = t1 / nt;
  feats[(size_t)n * C_DIM + c0] = a0;
  feats[(size_t)n * C_DIM + c1] = a1;

  red[threadIdx.x] = a0 * b0 + a1 * b1;
  __syncthreads();
  for (int s = 128; s > 0; s >>= 1) {
    if (threadIdx.x < s) red[threadIdx.x] += red[threadIdx.x + s];
    __syncthreads();
  }
  if (threadIdx.x == 0)
    out_logits[(size_t)n * L_ROW] = red[0] / 0.07f;   // l_pos / temperature
}

// ---------------------------------------------------------------------------
// K5: l_neg = feats(1024x512) @ queue(512x3072), f32 VALU GEMM, 64x64x32
// tiles, 4x4 register micro-tile per thread. Mask fused in epilogue.
// ---------------------------------------------------------------------------
#define BM 64
#define BN 64
#define BK 32
__global__ __launch_bounds__(256) void k_gemm(
    const float* __restrict__ A,    // feats [N_SAMP][C_DIM]
    const float* __restrict__ Bq,   // queue [C_DIM][K_Q]
    const int* __restrict__ labels, // shuffled labels [N_SAMP]
    const int* __restrict__ qlab,   // queue_labels [K_Q]
    float* __restrict__ out) {
  __shared__ float As[BK][BM];
  __shared__ float Bs[BK][BN];
  int bm = blockIdx.x * BM;
  int bn = blockIdx.y * BN;
  int tid = threadIdx.x;
  int tx = tid & 15, ty = tid >> 4;

  float acc[4][4] = {};
  for (int k0 = 0; k0 < C_DIM; k0 += BK) {
    // stage A: 64 rows x 32 k (transposed into As[k][m])
#pragma unroll
    for (int it = 0; it < 2; ++it) {
      int lin = tid + it * 256;        // 0..511
      int r = lin >> 3;                // 0..63
      int g = lin & 7;                 // 0..7 (float4 group in k)
      float4 v = *(const float4*)(A + (size_t)(bm + r) * C_DIM + k0 + g * 4);
      As[g * 4 + 0][r] = v.x; As[g * 4 + 1][r] = v.y;
      As[g * 4 + 2][r] = v.z; As[g * 4 + 3][r] = v.w;
    }
    // stage B: 32 k x 64 cols
#pragma unroll
    for (int it = 0; it < 2; ++it) {
      int lin = tid + it * 256;
      int kr = lin >> 4;               // 0..31
      int g = lin & 15;                // 0..15
      float4 v = *(const float4*)(Bq + (size_t)(k0 + kr) * K_Q + bn + g * 4);
      *(float4*)&Bs[kr][g * 4] = v;
    }
    __syncthreads();
#pragma unroll
    for (int k = 0; k < BK; ++k) {
      float a4[4], b4[4];
      *(float4*)a4 = *(const float4*)&As[k][ty * 4];
      *(float4*)b4 = *(const float4*)&Bs[k][tx * 4];
#pragma unroll
      for (int i = 0; i < 4; ++i)
#pragma unroll
        for (int j = 0; j < 4; ++j)
          acc[i][j] = fmaf(a4[i], b4[j], acc[i][j]);
    }
    __syncthreads();
  }

  float* out_mask = out + (size_t)N_SAMP * L_ROW;
#pragma unroll
  for (int i = 0; i < 4; ++i) {
    int row = bm + ty * 4 + i;
    int lab = labels[row];
    float* lrow = out + (size_t)row * L_ROW + 1 + bn + tx * 4;
    float* mrow = out_mask + (size_t)row * K_Q + bn + tx * 4;
#pragma unroll
    for (int j = 0; j < 4; ++j) {
      lrow[j] = acc[i][j] / 0.07f;
      mrow[j] = (lab == qlab[bn + tx * 4 + j]) ? 1.0f : 0.0f;
    }
  }
}

// ---------------------------------------------------------------------------
// Launch
// ---------------------------------------------------------------------------
extern "C" void kernel_launch(void* const* d_in, const int* in_sizes, int n_in,
                              void* d_out, int out_size, void* d_ws, size_t ws_size,
                              hipStream_t stream) {
  const float* fs     = (const float*)d_in[1];
  const float* ft     = (const float*)d_in[2];
  const int*   target = (const int*)d_in[3];
  const float* queue  = (const float*)d_in[4];
  const int*   qlab   = (const int*)d_in[5];
  float* out = (float*)d_out;

  // ws layout (all 256B-aligned)
  char* ws = (char*)d_ws;
  int*   cnt    = (int*)(ws + 0);
  int*   samp   = (int*)(ws + 256);
  int*   idxf   = (int*)(ws + 256 + 4096);
  int*   labs   = (int*)(ws + 256 + 8192);
  int*   lists  = (int*)(ws + 256 + 12288);                 // 4*32768*4 B
  float* feats  = (float*)(ws + 256 + 12288 + 4 * N_PIX * 4);

  // --- host-side RNG key derivation (pure CPU math; identical every call) ---
  uint32_t ck[5][2];
  // fold-like split: keys[i] = TF(key, hi=0, lo=i)
  for (int i = 0; i < 5; ++i)
    tf2x32(0u, 42u, 0u, (uint32_t)i, ck[i][0], ck[i][1]);
  // subkey = split(keys[4], 2)[1] = TF(keys[4], 0, 1)
  uint32_t sk0, sk1;
  tf2x32(ck[4][0], ck[4][1], 0u, 1u, sk0, sk1);

  float* out_labels = out + (size_t)N_SAMP * L_ROW + (size_t)N_SAMP * K_Q;

  k_zero<<<1, 64, 0, stream>>>(cnt);
  k_compact<<<N_PIX / 256, 256, 0, stream>>>(target, cnt, lists);
  k_sample<<<dim3(NQ, NCLS), 256, 0, stream>>>(
      cnt, lists, samp,
      ck[0][0], ck[0][1], ck[1][0], ck[1][1],
      ck[2][0], ck[2][1], ck[3][0], ck[3][1]);
  k_perm<<<16, 64, 0, stream>>>(samp, idxf, labs, out_labels, sk0, sk1);
  k_gather<<<N_SAMP, 256, 0, stream>>>(fs, ft, idxf, feats, out);
  k_gemm<<<dim3(N_SAMP / BM, K_Q / BN), 256, 0, stream>>>(
      feats, queue, labs, qlab, out);
}

// Round 6
// 258.744 us; speedup vs baseline: 1.7837x; 1.0744x over previous
//
#include <hip/hip_runtime.h>
#include <stdint.h>

// ---------------------------------------------------------------------------
// Problem constants
// ---------------------------------------------------------------------------
#define N_PIX   32768      // B*H*W = 8*64*64
#define C_DIM   512
#define K_Q     3072
#define NCLS    4
#define NQ      256
#define N_SAMP  1024       // NCLS*NQ
#define HW      4096       // H*W
#define L_ROW   3073       // 1 + K_Q
#define KH      1024       // stored split-K: [hi(512) | lo(512)]
#define KP      1536       // effective bf16 GEMM K' = 3 terms * 512

typedef float f32x4 __attribute__((ext_vector_type(4)));
typedef short s16x8 __attribute__((ext_vector_type(8)));   // 8 bf16 as shorts (guide-verified MFMA operand type)

__device__ inline unsigned short f2bf(float f) {           // RNE f32->bf16
  uint32_t u = __float_as_uint(f);
  return (unsigned short)((u + 0x7FFFu + ((u >> 16) & 1u)) >> 16);
}
__device__ inline float bf2f(unsigned short h) {
  return __uint_as_float(((uint32_t)h) << 16);
}

// ---------------------------------------------------------------------------
// Threefry2x32-20 (jax partitionable threefry — VERIFIED R1)
// ---------------------------------------------------------------------------
__host__ __device__ inline void tf2x32(uint32_t k0, uint32_t k1,
                                       uint32_t x0, uint32_t x1,
                                       uint32_t& o0, uint32_t& o1) {
  uint32_t ks2 = k0 ^ k1 ^ 0x1BD11BDAu;
  x0 += k0; x1 += k1;
#define ROTL_(v,d) (((v)<<(d))|((v)>>(32-(d))))
#define RND_(r) { x0 += x1; x1 = ROTL_(x1, r); x1 ^= x0; }
  RND_(13) RND_(15) RND_(26) RND_(6)
  x0 += k1; x1 += ks2 + 1u;
  RND_(17) RND_(29) RND_(16) RND_(24)
  x0 += ks2; x1 += k0 + 2u;
  RND_(13) RND_(15) RND_(26) RND_(6)
  x0 += k0; x1 += k1 + 3u;
  RND_(17) RND_(29) RND_(16) RND_(24)
  x0 += k1; x1 += ks2 + 4u;
  RND_(13) RND_(15) RND_(26) RND_(6)
  x0 += ks2; x1 += k0 + 5u;
  o0 = x0; o1 = x1;
#undef RND_
#undef ROTL_
}

// ---------------------------------------------------------------------------
// K0: zero per-class counters
// ---------------------------------------------------------------------------
__global__ void k_zero(int* cnt) {
  if (threadIdx.x < NCLS) cnt[threadIdx.x] = 0;
}

// ---------------------------------------------------------------------------
// K1: compact valid-pixel lists per class (LDS histogram; fixed in R3)
// ---------------------------------------------------------------------------
__global__ __launch_bounds__(256) void k_compact(const int* __restrict__ target,
                                                 int* __restrict__ cnt,
                                                 int* __restrict__ lists) {
  __shared__ int lcnt[NCLS];
  __shared__ int lbase[NCLS];
  int tid = threadIdx.x;
  if (tid < NCLS) lcnt[tid] = 0;
  __syncthreads();
  int p = blockIdx.x * 256 + tid;
  int c = target[p];
  int lpos = atomicAdd(&lcnt[c], 1);
  __syncthreads();
  if (tid < NCLS) lbase[tid] = atomicAdd(&cnt[tid], lcnt[tid]);
  __syncthreads();
  lists[c * N_PIX + lbase[c] + lpos] = p;
}

// ---------------------------------------------------------------------------
// K2: Gumbel-max sampling == argmax over valid pixels of raw uniform bits.
// ---------------------------------------------------------------------------
__global__ __launch_bounds__(256) void k_sample(
    const int* __restrict__ cnt, const int* __restrict__ lists,
    int* __restrict__ samp,
    uint32_t k0a, uint32_t k0b, uint32_t k1a, uint32_t k1b,
    uint32_t k2a, uint32_t k2b, uint32_t k3a, uint32_t k3b) {
  int c = blockIdx.y;
  int q = blockIdx.x;
  uint32_t ka, kb;
  if      (c == 0) { ka = k0a; kb = k0b; }
  else if (c == 1) { ka = k1a; kb = k1b; }
  else if (c == 2) { ka = k2a; kb = k2b; }
  else             { ka = k3a; kb = k3b; }

  int nv = cnt[c];
  const int* lst = lists + c * N_PIX;
  unsigned long long best = 0ull;
  for (int t = threadIdx.x; t < nv; t += 256) {
    int p = lst[t];
    uint32_t j = (uint32_t)(q * N_PIX + p);
    uint32_t o0, o1;
    tf2x32(ka, kb, 0u, j, o0, o1);
    uint32_t bits = o0 ^ o1;
    unsigned long long v =
        ((unsigned long long)(bits >> 9) << 15) | (unsigned)(32767 - p);
    if (v > best) best = v;
  }
  __shared__ unsigned long long red[256];
  red[threadIdx.x] = best;
  __syncthreads();
  for (int s = 128; s > 0; s >>= 1) {
    if (threadIdx.x < s && red[threadIdx.x + s] > red[threadIdx.x])
      red[threadIdx.x] = red[threadIdx.x + s];
    __syncthreads();
  }
  if (threadIdx.x == 0)
    samp[c * NQ + q] = 32767 - (int)(red[0] & 0x7FFFull);
}

// ---------------------------------------------------------------------------
// K3: shuffle = stable sort by random u32 keys; 16 blocks x 64 threads.
// ---------------------------------------------------------------------------
__global__ __launch_bounds__(64) void k_perm(
    const int* __restrict__ samp, int* __restrict__ idx_final,
    int* __restrict__ labels_shuf, float* __restrict__ out_labels,
    uint32_t sk0, uint32_t sk1) {
  __shared__ uint32_t keys_s[N_SAMP];
  int lt = threadIdx.x;
  for (int t = lt; t < N_SAMP; t += 64) {
    uint32_t o0, o1;
    tf2x32(sk0, sk1, 0u, (uint32_t)t, o0, o1);
    keys_s[t] = o0 ^ o1;
  }
  __syncthreads();
  int i = blockIdx.x * 64 + lt;
  uint32_t ki = keys_s[i];
  int rank = 0;
#pragma unroll 4
  for (int j = 0; j < N_SAMP; ++j) {
    uint32_t kj = keys_s[j];
    rank += (int)((kj < ki) | ((kj == ki) & (j < i)));
  }
  idx_final[rank] = samp[i];
  int lab = i >> 8;
  labels_shuf[rank] = lab;
  out_labels[rank] = (float)lab;
}

// ---------------------------------------------------------------------------
// K4: gather sampled rows, L2-normalize, write l_pos (f32) and A2 bf16
// split rows: A2[m][0:512]=hi(feat), A2[m][512:1024]=lo(feat).
// ---------------------------------------------------------------------------
__global__ __launch_bounds__(256) void k_gather(
    const float* __restrict__ fs, const float* __restrict__ ft,
    const int* __restrict__ idx_final, unsigned short* __restrict__ A2,
    float* __restrict__ out_logits) {
  int n = blockIdx.x;
  int p = idx_final[n];
  int b = p >> 12;
  int hw = p & (HW - 1);
  const float* fsb = fs + (size_t)b * C_DIM * HW + hw;
  const float* ftb = ft + (size_t)b * C_DIM * HW + hw;
  int c0 = threadIdx.x, c1 = threadIdx.x + 256;
  float s0 = fsb[(size_t)c0 * HW], s1 = fsb[(size_t)c1 * HW];
  float t0 = ftb[(size_t)c0 * HW], t1 = ftb[(size_t)c1 * HW];

  __shared__ float red[256];
  __shared__ float ns_sh, nt_sh;

  red[threadIdx.x] = s0 * s0 + s1 * s1;
  __syncthreads();
  for (int s = 128; s > 0; s >>= 1) {
    if (threadIdx.x < s) red[threadIdx.x] += red[threadIdx.x + s];
    __syncthreads();
  }
  if (threadIdx.x == 0) ns_sh = fmaxf(sqrtf(red[0]), 1e-12f);
  __syncthreads();

  red[threadIdx.x] = t0 * t0 + t1 * t1;
  __syncthreads();
  for (int s = 128; s > 0; s >>= 1) {
    if (threadIdx.x < s) red[threadIdx.x] += red[threadIdx.x + s];
    __syncthreads();
  }
  if (threadIdx.x == 0) nt_sh = fmaxf(sqrtf(red[0]), 1e-12f);
  __syncthreads();

  float ns = ns_sh, nt = nt_sh;
  float a0 = s0 / ns, a1 = s1 / ns;
  float b0 = t0 / nt, b1 = t1 / nt;

  unsigned short h0 = f2bf(a0), h1 = f2bf(a1);
  unsigned short l0 = f2bf(a0 - bf2f(h0)), l1 = f2bf(a1 - bf2f(h1));
  unsigned short* row = A2 + (size_t)n * KH;
  row[c0]       = h0;  row[c1]       = h1;
  row[512 + c0] = l0;  row[512 + c1] = l1;

  red[threadIdx.x] = a0 * b0 + a1 * b1;
  __syncthreads();
  for (int s = 128; s > 0; s >>= 1) {
    if (threadIdx.x < s) red[threadIdx.x] += red[threadIdx.x + s];
    __syncthreads();
  }
  if (threadIdx.x == 0)
    out_logits[(size_t)n * L_ROW] = red[0] * (1.0f / 0.07f);
}

// ---------------------------------------------------------------------------
// K_convq: queue [512][3072] f32 -> B2 [3072][1024] bf16 (B^T {hi|lo}).
// LDS-tiled transpose, odd stride 65 -> conflict-free column reads.
// ---------------------------------------------------------------------------
__global__ __launch_bounds__(256) void k_convq(const float* __restrict__ queue,
                                               unsigned short* __restrict__ B2) {
  __shared__ float tile[64][65];
  int tid = threadIdx.x;
  int n0 = blockIdx.x * 64;
  int k0 = blockIdx.y * 64;
#pragma unroll
  for (int it = 0; it < 4; ++it) {
    int r = (tid >> 4) + it * 16;
    int c4 = (tid & 15) * 4;
    float4 v = *(const float4*)(queue + (size_t)(k0 + r) * K_Q + n0 + c4);
    tile[r][c4 + 0] = v.x; tile[r][c4 + 1] = v.y;
    tile[r][c4 + 2] = v.z; tile[r][c4 + 3] = v.w;
  }
  __syncthreads();
  int tn = tid >> 2;
  int kc = (tid & 3) * 16;
  unsigned short* rowp = B2 + (size_t)(n0 + tn) * KH + k0 + kc;
#pragma unroll
  for (int g8 = 0; g8 < 2; ++g8) {
    s16x8 vhi, vlo;
#pragma unroll
    for (int j = 0; j < 8; ++j) {
      float v = tile[kc + g8 * 8 + j][tn];
      unsigned short h = f2bf(v);
      vhi[j] = (short)h;
      vlo[j] = (short)f2bf(v - bf2f(h));
    }
    *(s16x8*)(rowp + g8 * 8)       = vhi;
    *(s16x8*)(rowp + 512 + g8 * 8) = vlo;
  }
}

// ---------------------------------------------------------------------------
// K5: l_neg via bf16-split MFMA GEMM, K'=1536 (Ahi·Bhi + Ahi·Blo + Alo·Bhi
// via source-address selection over stored [hi|lo] halves).
// 128x128 tile, BK=64, 4 waves (2x2 of 64x64), reg-staged, XOR-swizzled LDS.
// ---------------------------------------------------------------------------
__global__ __launch_bounds__(256) void k_gemm(
    const unsigned short* __restrict__ A2,   // [1024][1024] {hi|lo}
    const unsigned short* __restrict__ B2,   // [3072][1024] {hi|lo} (B^T)
    float* __restrict__ out) {
  __shared__ unsigned short sAB[16384];      // A: [0,8192) B: [8192,16384) u16
  int tid  = threadIdx.x;
  int lane = tid & 63;
  int wave = tid >> 6;
  int wm = wave >> 1, wn = wave & 1;
  int bm = blockIdx.x * 128;
  int bn = blockIdx.y * 128;

  int rbase = wave * 32 + (lane >> 3);       // + c*8, c=0..3 -> rows 0..127
  int lcol  = (lane & 7) * 8;                // u16 col offset in 64-col window

  f32x4 acc[4][4] = {};
  s16x8 ra[4], rb[4];

  const int NSTEP = KP / 64;                 // 24
  {
#pragma unroll
    for (int c = 0; c < 4; ++c) {
      int r = rbase + c * 8;
      ra[c] = *(const s16x8*)(A2 + (size_t)(bm + r) * KH + lcol);
      rb[c] = *(const s16x8*)(B2 + (size_t)(bn + r) * KH + lcol);
    }
#pragma unroll
    for (int c = 0; c < 4; ++c) {
      int r = rbase + c * 8;
      int slot = ((lane & 7) ^ (r & 7)) * 8;
      *(s16x8*)&sAB[r * 64 + slot]        = ra[c];
      *(s16x8*)&sAB[8192 + r * 64 + slot] = rb[c];
    }
  }
  __syncthreads();

  for (int s = 0; s < NSTEP; ++s) {
    if (s + 1 < NSTEP) {                     // T14: issue next loads early
      int kp = (s + 1) * 64;
      int sA = (kp < 512) ? kp : kp - 512;   // [Ahi;Ahi;Alo]
      int sB = (kp < 1024) ? kp : kp - 1024; // [Bhi;Blo;Bhi]
#pragma unroll
      for (int c = 0; c < 4; ++c) {
        int r = rbase + c * 8;
        ra[c] = *(const s16x8*)(A2 + (size_t)(bm + r) * KH + sA + lcol);
        rb[c] = *(const s16x8*)(B2 + (size_t)(bn + r) * KH + sB + lcol);
      }
    }
#pragma unroll
    for (int kk = 0; kk < 2; ++kk) {
      int g = kk * 4 + (lane >> 4);
      s16x8 af[4], bfr[4];
#pragma unroll
      for (int mi = 0; mi < 4; ++mi) {
        int rowL = wm * 64 + mi * 16 + (lane & 15);
        af[mi] = *(s16x8*)&sAB[rowL * 64 + ((g ^ (rowL & 7)) << 3)];
      }
#pragma unroll
      for (int ni = 0; ni < 4; ++ni) {
        int rowN = wn * 64 + ni * 16 + (lane & 15);
        bfr[ni] = *(s16x8*)&sAB[8192 + rowN * 64 + ((g ^ (rowN & 7)) << 3)];
      }
#pragma unroll
      for (int mi = 0; mi < 4; ++mi)
#pragma unroll
        for (int ni = 0; ni < 4; ++ni)
          acc[mi][ni] = __builtin_amdgcn_mfma_f32_16x16x32_bf16(
              af[mi], bfr[ni], acc[mi][ni], 0, 0, 0);
    }
    __syncthreads();
    if (s + 1 < NSTEP) {
#pragma unroll
      for (int c = 0; c < 4; ++c) {
        int r = rbase + c * 8;
        int slot = ((lane & 7) ^ (r & 7)) * 8;
        *(s16x8*)&sAB[r * 64 + slot]        = ra[c];
        *(s16x8*)&sAB[8192 + r * 64 + slot] = rb[c];
      }
      __syncthreads();
    }
  }

  const float sc = 1.0f / 0.07f;
#pragma unroll
  for (int mi = 0; mi < 4; ++mi) {
#pragma unroll
    for (int ni = 0; ni < 4; ++ni) {
#pragma unroll
      for (int j = 0; j < 4; ++j) {
        int rl = wm * 64 + mi * 16 + ((lane >> 4) << 2) + j;
        int cl = wn * 64 + ni * 16 + (lane & 15);
        out[(size_t)(bm + rl) * L_ROW + 1 + (bn + cl)] = acc[mi][ni][j] * sc;
      }
    }
  }
}

// ---------------------------------------------------------------------------
// K_mask: mask[n][k] = (labels_shuf[n] == qlab[k]). Runs AFTER k_gemm so the
// mask region can serve as A2/B2 scratch during the GEMM (keeps ws at the
// R3-proven 528 KB footprint).
// ---------------------------------------------------------------------------
__global__ __launch_bounds__(256) void k_mask(const int* __restrict__ labels,
                                              const int* __restrict__ qlab,
                                              float* __restrict__ mask) {
  int row = blockIdx.x;
  int lab = labels[row];
  float* mrow = mask + (size_t)row * K_Q;
#pragma unroll
  for (int j = 0; j < 12; ++j) {
    int col = j * 256 + threadIdx.x;
    mrow[col] = (lab == qlab[col]) ? 1.0f : 0.0f;
  }
}

// ---------------------------------------------------------------------------
// Launch
// ---------------------------------------------------------------------------
extern "C" void kernel_launch(void* const* d_in, const int* in_sizes, int n_in,
                              void* d_out, int out_size, void* d_ws, size_t ws_size,
                              hipStream_t stream) {
  const float* fs     = (const float*)d_in[1];
  const float* ft     = (const float*)d_in[2];
  const int*   target = (const int*)d_in[3];
  const float* queue  = (const float*)d_in[4];
  const int*   qlab   = (const int*)d_in[5];
  float* out = (float*)d_out;

  // ws layout — 528 KB total (R3-proven footprint)
  char* ws = (char*)d_ws;
  int* cnt   = (int*)(ws + 0);
  int* samp  = (int*)(ws + 4096);
  int* idxf  = (int*)(ws + 8192);
  int* labs  = (int*)(ws + 12288);
  int* lists = (int*)(ws + 16384);                          // 512 KB

  // bf16 scratch lives in d_out's mask region (12.58 MB >= 6.29+2 MB),
  // overwritten by k_mask after the GEMM.
  float* maskBase = out + (size_t)N_SAMP * L_ROW;
  unsigned short* B2 = (unsigned short*)maskBase;                    // 6.29 MB
  unsigned short* A2 = (unsigned short*)maskBase + (size_t)K_Q * KH; // 2 MB

  // host-side RNG key derivation (partitionable threefry — verified R1)
  uint32_t ck[5][2];
  for (int i = 0; i < 5; ++i)
    tf2x32(0u, 42u, 0u, (uint32_t)i, ck[i][0], ck[i][1]);
  uint32_t sk0, sk1;
  tf2x32(ck[4][0], ck[4][1], 0u, 1u, sk0, sk1);

  float* out_labels = out + (size_t)N_SAMP * L_ROW + (size_t)N_SAMP * K_Q;

  k_zero<<<1, 64, 0, stream>>>(cnt);
  k_compact<<<N_PIX / 256, 256, 0, stream>>>(target, cnt, lists);
  k_convq<<<dim3(K_Q / 64, C_DIM / 64), 256, 0, stream>>>(queue, B2);
  k_sample<<<dim3(NQ, NCLS), 256, 0, stream>>>(
      cnt, lists, samp,
      ck[0][0], ck[0][1], ck[1][0], ck[1][1],
      ck[2][0], ck[2][1], ck[3][0], ck[3][1]);
  k_perm<<<16, 64, 0, stream>>>(samp, idxf, labs, out_labels, sk0, sk1);
  k_gather<<<N_SAMP, 256, 0, stream>>>(fs, ft, idxf, A2, out);
  k_gemm<<<dim3(N_SAMP / 128, K_Q / 128), 256, 0, stream>>>(A2, B2, out);
  k_mask<<<N_SAMP, 256, 0, stream>>>(labs, qlab, maskBase);
}

// Round 7
// 243.987 us; speedup vs baseline: 1.8915x; 1.0605x over previous
//
#include <hip/hip_runtime.h>
#include <stdint.h>

// ---------------------------------------------------------------------------
// Problem constants
// ---------------------------------------------------------------------------
#define N_PIX   32768      // B*H*W = 8*64*64
#define C_DIM   512
#define K_Q     3072
#define NCLS    4
#define NQ      256
#define N_SAMP  1024       // NCLS*NQ
#define HW      4096       // H*W
#define L_ROW   3073       // 1 + K_Q
#define KH      1024       // stored split-K: [hi(512) | lo(512)]
#define KP      1536       // effective bf16 GEMM K' = 3 terms * 512

typedef float f32x4 __attribute__((ext_vector_type(4)));
typedef short s16x8 __attribute__((ext_vector_type(8)));   // 8 bf16 as shorts

__device__ inline unsigned short f2bf(float f) {           // RNE f32->bf16
  uint32_t u = __float_as_uint(f);
  return (unsigned short)((u + 0x7FFFu + ((u >> 16) & 1u)) >> 16);
}
__device__ inline float bf2f(unsigned short h) {
  return __uint_as_float(((uint32_t)h) << 16);
}

// ---------------------------------------------------------------------------
// Threefry2x32-20 (jax partitionable threefry — VERIFIED R1)
// ---------------------------------------------------------------------------
__host__ __device__ inline void tf2x32(uint32_t k0, uint32_t k1,
                                       uint32_t x0, uint32_t x1,
                                       uint32_t& o0, uint32_t& o1) {
  uint32_t ks2 = k0 ^ k1 ^ 0x1BD11BDAu;
  x0 += k0; x1 += k1;
#define ROTL_(v,d) (((v)<<(d))|((v)>>(32-(d))))
#define RND_(r) { x0 += x1; x1 = ROTL_(x1, r); x1 ^= x0; }
  RND_(13) RND_(15) RND_(26) RND_(6)
  x0 += k1; x1 += ks2 + 1u;
  RND_(17) RND_(29) RND_(16) RND_(24)
  x0 += ks2; x1 += k0 + 2u;
  RND_(13) RND_(15) RND_(26) RND_(6)
  x0 += k0; x1 += k1 + 3u;
  RND_(17) RND_(29) RND_(16) RND_(24)
  x0 += k1; x1 += ks2 + 4u;
  RND_(13) RND_(15) RND_(26) RND_(6)
  x0 += ks2; x1 += k0 + 5u;
  o0 = x0; o1 = x1;
#undef RND_
#undef ROTL_
}

// ---------------------------------------------------------------------------
// K_convq: queue [512][3072] f32 -> B2 [3072][1024] bf16 (B^T {hi|lo}).
// Also zeroes the per-class counters (fused k_zero; runs before k_compact
// in stream order). LDS-tiled transpose, stride 65 -> conflict-free.
// ---------------------------------------------------------------------------
__global__ __launch_bounds__(256) void k_convq(const float* __restrict__ queue,
                                               unsigned short* __restrict__ B2,
                                               int* __restrict__ cnt) {
  if (blockIdx.x == 0 && blockIdx.y == 0 && threadIdx.x < NCLS)
    cnt[threadIdx.x] = 0;
  __shared__ float tile[64][65];
  int tid = threadIdx.x;
  int n0 = blockIdx.x * 64;
  int k0 = blockIdx.y * 64;
#pragma unroll
  for (int it = 0; it < 4; ++it) {
    int r = (tid >> 4) + it * 16;
    int c4 = (tid & 15) * 4;
    float4 v = *(const float4*)(queue + (size_t)(k0 + r) * K_Q + n0 + c4);
    tile[r][c4 + 0] = v.x; tile[r][c4 + 1] = v.y;
    tile[r][c4 + 2] = v.z; tile[r][c4 + 3] = v.w;
  }
  __syncthreads();
  int tn = tid >> 2;
  int kc = (tid & 3) * 16;
  unsigned short* rowp = B2 + (size_t)(n0 + tn) * KH + k0 + kc;
#pragma unroll
  for (int g8 = 0; g8 < 2; ++g8) {
    s16x8 vhi, vlo;
#pragma unroll
    for (int j = 0; j < 8; ++j) {
      float v = tile[kc + g8 * 8 + j][tn];
      unsigned short h = f2bf(v);
      vhi[j] = (short)h;
      vlo[j] = (short)f2bf(v - bf2f(h));
    }
    *(s16x8*)(rowp + g8 * 8)       = vhi;
    *(s16x8*)(rowp + 512 + g8 * 8) = vlo;
  }
}

// ---------------------------------------------------------------------------
// K1: compact valid-pixel lists per class (LDS histogram; fixed in R3)
// ---------------------------------------------------------------------------
__global__ __launch_bounds__(256) void k_compact(const int* __restrict__ target,
                                                 int* __restrict__ cnt,
                                                 int* __restrict__ lists) {
  __shared__ int lcnt[NCLS];
  __shared__ int lbase[NCLS];
  int tid = threadIdx.x;
  if (tid < NCLS) lcnt[tid] = 0;
  __syncthreads();
  int p = blockIdx.x * 256 + tid;
  int c = target[p];
  int lpos = atomicAdd(&lcnt[c], 1);
  __syncthreads();
  if (tid < NCLS) lbase[tid] = atomicAdd(&cnt[tid], lcnt[tid]);
  __syncthreads();
  lists[c * N_PIX + lbase[c] + lpos] = p;
}

// ---------------------------------------------------------------------------
// K2: Gumbel-max sampling == argmax over valid pixels of raw uniform bits.
// ---------------------------------------------------------------------------
__global__ __launch_bounds__(256) void k_sample(
    const int* __restrict__ cnt, const int* __restrict__ lists,
    int* __restrict__ samp,
    uint32_t k0a, uint32_t k0b, uint32_t k1a, uint32_t k1b,
    uint32_t k2a, uint32_t k2b, uint32_t k3a, uint32_t k3b) {
  int c = blockIdx.y;
  int q = blockIdx.x;
  uint32_t ka, kb;
  if      (c == 0) { ka = k0a; kb = k0b; }
  else if (c == 1) { ka = k1a; kb = k1b; }
  else if (c == 2) { ka = k2a; kb = k2b; }
  else             { ka = k3a; kb = k3b; }

  int nv = cnt[c];
  const int* lst = lists + c * N_PIX;
  unsigned long long best = 0ull;
  for (int t = threadIdx.x; t < nv; t += 256) {
    int p = lst[t];
    uint32_t j = (uint32_t)(q * N_PIX + p);
    uint32_t o0, o1;
    tf2x32(ka, kb, 0u, j, o0, o1);
    uint32_t bits = o0 ^ o1;
    unsigned long long v =
        ((unsigned long long)(bits >> 9) << 15) | (unsigned)(32767 - p);
    if (v > best) best = v;
  }
  __shared__ unsigned long long red[256];
  red[threadIdx.x] = best;
  __syncthreads();
  for (int s = 128; s > 0; s >>= 1) {
    if (threadIdx.x < s && red[threadIdx.x + s] > red[threadIdx.x])
      red[threadIdx.x] = red[threadIdx.x + s];
    __syncthreads();
  }
  if (threadIdx.x == 0)
    samp[c * NQ + q] = 32767 - (int)(red[0] & 0x7FFFull);
}

// ---------------------------------------------------------------------------
// K3: shuffle = stable sort by random u32 keys; 16 blocks x 64 threads.
// ---------------------------------------------------------------------------
__global__ __launch_bounds__(64) void k_perm(
    const int* __restrict__ samp, int* __restrict__ idx_final,
    int* __restrict__ labels_shuf, float* __restrict__ out_labels,
    uint32_t sk0, uint32_t sk1) {
  __shared__ uint32_t keys_s[N_SAMP];
  int lt = threadIdx.x;
  for (int t = lt; t < N_SAMP; t += 64) {
    uint32_t o0, o1;
    tf2x32(sk0, sk1, 0u, (uint32_t)t, o0, o1);
    keys_s[t] = o0 ^ o1;
  }
  __syncthreads();
  int i = blockIdx.x * 64 + lt;
  uint32_t ki = keys_s[i];
  int rank = 0;
#pragma unroll 4
  for (int j = 0; j < N_SAMP; ++j) {
    uint32_t kj = keys_s[j];
    rank += (int)((kj < ki) | ((kj == ki) & (j < i)));
  }
  idx_final[rank] = samp[i];
  int lab = i >> 8;
  labels_shuf[rank] = lab;
  out_labels[rank] = (float)lab;
}

// ---------------------------------------------------------------------------
// K4: gather sampled rows, L2-normalize, write l_pos (f32) and A2 bf16
// split rows: A2[m][0:512]=hi(feat), A2[m][512:1024]=lo(feat).
// ---------------------------------------------------------------------------
__global__ __launch_bounds__(256) void k_gather(
    const float* __restrict__ fs, const float* __restrict__ ft,
    const int* __restrict__ idx_final, unsigned short* __restrict__ A2,
    float* __restrict__ out_logits) {
  int n = blockIdx.x;
  int p = idx_final[n];
  int b = p >> 12;
  int hw = p & (HW - 1);
  const float* fsb = fs + (size_t)b * C_DIM * HW + hw;
  const float* ftb = ft + (size_t)b * C_DIM * HW + hw;
  int c0 = threadIdx.x, c1 = threadIdx.x + 256;
  float s0 = fsb[(size_t)c0 * HW], s1 = fsb[(size_t)c1 * HW];
  float t0 = ftb[(size_t)c0 * HW], t1 = ftb[(size_t)c1 * HW];

  __shared__ float red[256];
  __shared__ float ns_sh, nt_sh;

  red[threadIdx.x] = s0 * s0 + s1 * s1;
  __syncthreads();
  for (int s = 128; s > 0; s >>= 1) {
    if (threadIdx.x < s) red[threadIdx.x] += red[threadIdx.x + s];
    __syncthreads();
  }
  if (threadIdx.x == 0) ns_sh = fmaxf(sqrtf(red[0]), 1e-12f);
  __syncthreads();

  red[threadIdx.x] = t0 * t0 + t1 * t1;
  __syncthreads();
  for (int s = 128; s > 0; s >>= 1) {
    if (threadIdx.x < s) red[threadIdx.x] += red[threadIdx.x + s];
    __syncthreads();
  }
  if (threadIdx.x == 0) nt_sh = fmaxf(sqrtf(red[0]), 1e-12f);
  __syncthreads();

  float ns = ns_sh, nt = nt_sh;
  float a0 = s0 / ns, a1 = s1 / ns;
  float b0 = t0 / nt, b1 = t1 / nt;

  unsigned short h0 = f2bf(a0), h1 = f2bf(a1);
  unsigned short l0 = f2bf(a0 - bf2f(h0)), l1 = f2bf(a1 - bf2f(h1));
  unsigned short* row = A2 + (size_t)n * KH;
  row[c0]       = h0;  row[c1]       = h1;
  row[512 + c0] = l0;  row[512 + c1] = l1;

  red[threadIdx.x] = a0 * b0 + a1 * b1;
  __syncthreads();
  for (int s = 128; s > 0; s >>= 1) {
    if (threadIdx.x < s) red[threadIdx.x] += red[threadIdx.x + s];
    __syncthreads();
  }
  if (threadIdx.x == 0)
    out_logits[(size_t)n * L_ROW] = red[0] * (1.0f / 0.07f);
}

// ---------------------------------------------------------------------------
// K5: l_neg via bf16-split MFMA GEMM, K'=1536.
// R6 post-mortem: 128x128 tile = 192 blocks = 0.75/CU (64 CUs idle, 1
// wave/SIMD, barrier drains exposed). Now 64x64 tile = 768 blocks = 3/CU
// (3 waves/SIMD -> m114 inter-wave overlap hides staging+barriers).
// Same MFMA count, same accumulation order (bit-identical output).
// Mask write fused into epilogue (A2/B2 now live in ws, no aliasing).
// ---------------------------------------------------------------------------
__global__ __launch_bounds__(256) void k_gemm(
    const unsigned short* __restrict__ A2,   // [1024][1024] {hi|lo}
    const unsigned short* __restrict__ B2,   // [3072][1024] {hi|lo} (B^T)
    const int* __restrict__ labels,
    const int* __restrict__ qlab,
    float* __restrict__ out) {
  __shared__ unsigned short sAB[8192];       // A: [0,4096) B: [4096,8192) u16
  int tid  = threadIdx.x;
  int lane = tid & 63;
  int wave = tid >> 6;
  int wm = wave >> 1, wn = wave & 1;         // 2x2 waves -> 32x32 each
  int bm = blockIdx.x * 64;                  // 16 m-tiles
  int bn = blockIdx.y * 64;                  // 48 n-tiles

  // staging: 512 chunks of 8 u16 per matrix; thread t handles chunks t, t+256
  int r0 = tid >> 3;                         // rows r0, r0+32
  int g0 = tid & 7;                          // col8 group
  int slot0 = ((g0 ^ (r0 & 7)) << 3);        // same for r0+32 ((r0+32)&7==r0&7)

  f32x4 acc[2][2] = {};
  s16x8 ra[2], rb[2];

  const int NSTEP = KP / 64;                 // 24
  {
    ra[0] = *(const s16x8*)(A2 + (size_t)(bm + r0)      * KH + g0 * 8);
    ra[1] = *(const s16x8*)(A2 + (size_t)(bm + r0 + 32) * KH + g0 * 8);
    rb[0] = *(const s16x8*)(B2 + (size_t)(bn + r0)      * KH + g0 * 8);
    rb[1] = *(const s16x8*)(B2 + (size_t)(bn + r0 + 32) * KH + g0 * 8);
    *(s16x8*)&sAB[r0 * 64 + slot0]               = ra[0];
    *(s16x8*)&sAB[(r0 + 32) * 64 + slot0]        = ra[1];
    *(s16x8*)&sAB[4096 + r0 * 64 + slot0]        = rb[0];
    *(s16x8*)&sAB[4096 + (r0 + 32) * 64 + slot0] = rb[1];
  }
  __syncthreads();

  for (int s = 0; s < NSTEP; ++s) {
    if (s + 1 < NSTEP) {                     // T14: issue next loads early
      int kp = (s + 1) * 64;
      int sA = (kp < 512) ? kp : kp - 512;   // [Ahi;Ahi;Alo]
      int sB = (kp < 1024) ? kp : kp - 1024; // [Bhi;Blo;Bhi]
      ra[0] = *(const s16x8*)(A2 + (size_t)(bm + r0)      * KH + sA + g0 * 8);
      ra[1] = *(const s16x8*)(A2 + (size_t)(bm + r0 + 32) * KH + sA + g0 * 8);
      rb[0] = *(const s16x8*)(B2 + (size_t)(bn + r0)      * KH + sB + g0 * 8);
      rb[1] = *(const s16x8*)(B2 + (size_t)(bn + r0 + 32) * KH + sB + g0 * 8);
    }
#pragma unroll
    for (int kk = 0; kk < 2; ++kk) {
      int g = kk * 4 + (lane >> 4);
      s16x8 af[2], bfr[2];
#pragma unroll
      for (int mi = 0; mi < 2; ++mi) {
        int rowL = wm * 32 + mi * 16 + (lane & 15);
        af[mi] = *(s16x8*)&sAB[rowL * 64 + ((g ^ (rowL & 7)) << 3)];
      }
#pragma unroll
      for (int ni = 0; ni < 2; ++ni) {
        int rowN = wn * 32 + ni * 16 + (lane & 15);
        bfr[ni] = *(s16x8*)&sAB[4096 + rowN * 64 + ((g ^ (rowN & 7)) << 3)];
      }
#pragma unroll
      for (int mi = 0; mi < 2; ++mi)
#pragma unroll
        for (int ni = 0; ni < 2; ++ni)
          acc[mi][ni] = __builtin_amdgcn_mfma_f32_16x16x32_bf16(
              af[mi], bfr[ni], acc[mi][ni], 0, 0, 0);
    }
    __syncthreads();
    if (s + 1 < NSTEP) {
      *(s16x8*)&sAB[r0 * 64 + slot0]               = ra[0];
      *(s16x8*)&sAB[(r0 + 32) * 64 + slot0]        = ra[1];
      *(s16x8*)&sAB[4096 + r0 * 64 + slot0]        = rb[0];
      *(s16x8*)&sAB[4096 + (r0 + 32) * 64 + slot0] = rb[1];
      __syncthreads();
    }
  }

  // epilogue: stage labels in now-free LDS; write logits + mask
  int* labsh = (int*)sAB;                    // [0:64)=row labels [64:128)=qlab
  if (tid < 64)            labsh[tid] = labels[bm + tid];
  else if (tid < 128)      labsh[tid] = qlab[bn + (tid - 64)];
  __syncthreads();

  float* out_mask = out + (size_t)N_SAMP * L_ROW;
  const float sc = 1.0f / 0.07f;
#pragma unroll
  for (int mi = 0; mi < 2; ++mi) {
#pragma unroll
    for (int ni = 0; ni < 2; ++ni) {
#pragma unroll
      for (int j = 0; j < 4; ++j) {
        int rl = wm * 32 + mi * 16 + ((lane >> 4) << 2) + j;
        int cl = wn * 32 + ni * 16 + (lane & 15);
        int row = bm + rl, col = bn + cl;
        out[(size_t)row * L_ROW + 1 + col] = acc[mi][ni][j] * sc;
        out_mask[(size_t)row * K_Q + col] =
            (labsh[rl] == labsh[64 + cl]) ? 1.0f : 0.0f;
      }
    }
  }
}

// ---------------------------------------------------------------------------
// Launch — 6 dispatches (was 8): k_zero fused into k_convq, k_mask into
// k_gemm. A2/B2 in ws (ws_size = 256 MiB, verified R6 via poison-fill size).
// ---------------------------------------------------------------------------
extern "C" void kernel_launch(void* const* d_in, const int* in_sizes, int n_in,
                              void* d_out, int out_size, void* d_ws, size_t ws_size,
                              hipStream_t stream) {
  const float* fs     = (const float*)d_in[1];
  const float* ft     = (const float*)d_in[2];
  const int*   target = (const int*)d_in[3];
  const float* queue  = (const float*)d_in[4];
  const int*   qlab   = (const int*)d_in[5];
  float* out = (float*)d_out;

  // ws layout (~10.3 MB of the 256 MiB)
  char* ws = (char*)d_ws;
  int* cnt   = (int*)(ws + 0);
  int* samp  = (int*)(ws + 4096);
  int* idxf  = (int*)(ws + 8192);
  int* labs  = (int*)(ws + 12288);
  int* lists = (int*)(ws + 16384);                          // 512 KB
  unsigned short* A2 = (unsigned short*)(ws + (1u << 20));  // 2 MB @ 1 MiB
  unsigned short* B2 = (unsigned short*)(ws + (4u << 20));  // 6.29 MB @ 4 MiB

  // host-side RNG key derivation (partitionable threefry — verified R1)
  uint32_t ck[5][2];
  for (int i = 0; i < 5; ++i)
    tf2x32(0u, 42u, 0u, (uint32_t)i, ck[i][0], ck[i][1]);
  uint32_t sk0, sk1;
  tf2x32(ck[4][0], ck[4][1], 0u, 1u, sk0, sk1);

  float* out_labels = out + (size_t)N_SAMP * L_ROW + (size_t)N_SAMP * K_Q;

  k_convq<<<dim3(K_Q / 64, C_DIM / 64), 256, 0, stream>>>(queue, B2, cnt);
  k_compact<<<N_PIX / 256, 256, 0, stream>>>(target, cnt, lists);
  k_sample<<<dim3(NQ, NCLS), 256, 0, stream>>>(
      cnt, lists, samp,
      ck[0][0], ck[0][1], ck[1][0], ck[1][1],
      ck[2][0], ck[2][1], ck[3][0], ck[3][1]);
  k_perm<<<16, 64, 0, stream>>>(samp, idxf, labs, out_labels, sk0, sk1);
  k_gather<<<N_SAMP, 256, 0, stream>>>(fs, ft, idxf, A2, out);
  k_gemm<<<dim3(N_SAMP / 64, K_Q / 64), 256, 0, stream>>>(
      A2, B2, labs, qlab, out);
}

// Round 9
// 242.923 us; speedup vs baseline: 1.8998x; 1.0044x over previous
//
#include <hip/hip_runtime.h>
#include <stdint.h>

// ---------------------------------------------------------------------------
// Problem constants
// ---------------------------------------------------------------------------
#define N_PIX   32768      // B*H*W = 8*64*64
#define C_DIM   512
#define K_Q     3072
#define NCLS    4
#define NQ      256
#define N_SAMP  1024       // NCLS*NQ
#define HW      4096       // H*W
#define L_ROW   3073       // 1 + K_Q
#define KH      1024       // stored split-K: [hi(512) | lo(512)]
#define KP      1536       // effective bf16 GEMM K' = 3 terms * 512

typedef float f32x4 __attribute__((ext_vector_type(4)));
typedef short s16x8 __attribute__((ext_vector_type(8)));   // 8 bf16 as shorts

__device__ inline unsigned short f2bf(float f) {           // RNE f32->bf16
  uint32_t u = __float_as_uint(f);
  return (unsigned short)((u + 0x7FFFu + ((u >> 16) & 1u)) >> 16);
}
__device__ inline float bf2f(unsigned short h) {
  return __uint_as_float(((uint32_t)h) << 16);
}

// ---------------------------------------------------------------------------
// Threefry2x32-20 (jax partitionable threefry — VERIFIED R1)
// ---------------------------------------------------------------------------
__host__ __device__ inline void tf2x32(uint32_t k0, uint32_t k1,
                                       uint32_t x0, uint32_t x1,
                                       uint32_t& o0, uint32_t& o1) {
  uint32_t ks2 = k0 ^ k1 ^ 0x1BD11BDAu;
  x0 += k0; x1 += k1;
#define ROTL_(v,d) (((v)<<(d))|((v)>>(32-(d))))
#define RND_(r) { x0 += x1; x1 = ROTL_(x1, r); x1 ^= x0; }
  RND_(13) RND_(15) RND_(26) RND_(6)
  x0 += k1; x1 += ks2 + 1u;
  RND_(17) RND_(29) RND_(16) RND_(24)
  x0 += ks2; x1 += k0 + 2u;
  RND_(13) RND_(15) RND_(26) RND_(6)
  x0 += k0; x1 += k1 + 3u;
  RND_(17) RND_(29) RND_(16) RND_(24)
  x0 += k1; x1 += ks2 + 4u;
  RND_(13) RND_(15) RND_(26) RND_(6)
  x0 += ks2; x1 += k0 + 5u;
  o0 = x0; o1 = x1;
#undef RND_
#undef ROTL_
}

// ---------------------------------------------------------------------------
// K_convq: queue [512][3072] f32 -> B2 [3072][1024] bf16 (B^T {hi|lo}).
// Also zeroes the per-class counters (fused k_zero; stream-ordered before
// k_compact). LDS-tiled transpose, stride 65 -> conflict-free.
// ---------------------------------------------------------------------------
__global__ __launch_bounds__(256) void k_convq(const float* __restrict__ queue,
                                               unsigned short* __restrict__ B2,
                                               int* __restrict__ cnt) {
  if (blockIdx.x == 0 && blockIdx.y == 0 && threadIdx.x < NCLS)
    cnt[threadIdx.x] = 0;
  __shared__ float tile[64][65];
  int tid = threadIdx.x;
  int n0 = blockIdx.x * 64;
  int k0 = blockIdx.y * 64;
#pragma unroll
  for (int it = 0; it < 4; ++it) {
    int r = (tid >> 4) + it * 16;
    int c4 = (tid & 15) * 4;
    float4 v = *(const float4*)(queue + (size_t)(k0 + r) * K_Q + n0 + c4);
    tile[r][c4 + 0] = v.x; tile[r][c4 + 1] = v.y;
    tile[r][c4 + 2] = v.z; tile[r][c4 + 3] = v.w;
  }
  __syncthreads();
  int tn = tid >> 2;
  int kc = (tid & 3) * 16;
  unsigned short* rowp = B2 + (size_t)(n0 + tn) * KH + k0 + kc;
#pragma unroll
  for (int g8 = 0; g8 < 2; ++g8) {
    s16x8 vhi, vlo;
#pragma unroll
    for (int j = 0; j < 8; ++j) {
      float v = tile[kc + g8 * 8 + j][tn];
      unsigned short h = f2bf(v);
      vhi[j] = (short)h;
      vlo[j] = (short)f2bf(v - bf2f(h));
    }
    *(s16x8*)(rowp + g8 * 8)       = vhi;
    *(s16x8*)(rowp + 512 + g8 * 8) = vlo;
  }
}

// ---------------------------------------------------------------------------
// K1: compact valid-pixel lists per class (LDS histogram; fixed in R3)
// ---------------------------------------------------------------------------
__global__ __launch_bounds__(256) void k_compact(const int* __restrict__ target,
                                                 int* __restrict__ cnt,
                                                 int* __restrict__ lists) {
  __shared__ int lcnt[NCLS];
  __shared__ int lbase[NCLS];
  int tid = threadIdx.x;
  if (tid < NCLS) lcnt[tid] = 0;
  __syncthreads();
  int p = blockIdx.x * 256 + tid;
  int c = target[p];
  int lpos = atomicAdd(&lcnt[c], 1);
  __syncthreads();
  if (tid < NCLS) lbase[tid] = atomicAdd(&cnt[tid], lcnt[tid]);
  __syncthreads();
  lists[c * N_PIX + lbase[c] + lpos] = p;
}

// ---------------------------------------------------------------------------
// K2: Gumbel-max sampling == argmax over valid pixels of raw uniform bits.
// ---------------------------------------------------------------------------
__global__ __launch_bounds__(256) void k_sample(
    const int* __restrict__ cnt, const int* __restrict__ lists,
    int* __restrict__ samp,
    uint32_t k0a, uint32_t k0b, uint32_t k1a, uint32_t k1b,
    uint32_t k2a, uint32_t k2b, uint32_t k3a, uint32_t k3b) {
  int c = blockIdx.y;
  int q = blockIdx.x;
  uint32_t ka, kb;
  if      (c == 0) { ka = k0a; kb = k0b; }
  else if (c == 1) { ka = k1a; kb = k1b; }
  else if (c == 2) { ka = k2a; kb = k2b; }
  else             { ka = k3a; kb = k3b; }

  int nv = cnt[c];
  const int* lst = lists + c * N_PIX;
  unsigned long long best = 0ull;
  for (int t = threadIdx.x; t < nv; t += 256) {
    int p = lst[t];
    uint32_t j = (uint32_t)(q * N_PIX + p);
    uint32_t o0, o1;
    tf2x32(ka, kb, 0u, j, o0, o1);
    uint32_t bits = o0 ^ o1;
    unsigned long long v =
        ((unsigned long long)(bits >> 9) << 15) | (unsigned)(32767 - p);
    if (v > best) best = v;
  }
  __shared__ unsigned long long red[256];
  red[threadIdx.x] = best;
  __syncthreads();
  for (int s = 128; s > 0; s >>= 1) {
    if (threadIdx.x < s && red[threadIdx.x + s] > red[threadIdx.x])
      red[threadIdx.x] = red[threadIdx.x + s];
    __syncthreads();
  }
  if (threadIdx.x == 0)
    samp[c * NQ + q] = 32767 - (int)(red[0] & 0x7FFFull);
}

// ---------------------------------------------------------------------------
// K3: shuffle = stable sort by random u32 keys; 16 blocks x 64 threads.
// ---------------------------------------------------------------------------
__global__ __launch_bounds__(64) void k_perm(
    const int* __restrict__ samp, int* __restrict__ idx_final,
    int* __restrict__ labels_shuf, float* __restrict__ out_labels,
    uint32_t sk0, uint32_t sk1) {
  __shared__ uint32_t keys_s[N_SAMP];
  int lt = threadIdx.x;
  for (int t = lt; t < N_SAMP; t += 64) {
    uint32_t o0, o1;
    tf2x32(sk0, sk1, 0u, (uint32_t)t, o0, o1);
    keys_s[t] = o0 ^ o1;
  }
  __syncthreads();
  int i = blockIdx.x * 64 + lt;
  uint32_t ki = keys_s[i];
  int rank = 0;
#pragma unroll 4
  for (int j = 0; j < N_SAMP; ++j) {
    uint32_t kj = keys_s[j];
    rank += (int)((kj < ki) | ((kj == ki) & (j < i)));
  }
  idx_final[rank] = samp[i];
  int lab = i >> 8;
  labels_shuf[rank] = lab;
  out_labels[rank] = (float)lab;
}

// ---------------------------------------------------------------------------
// K4 v2: ONE WAVE PER PIXEL (R8). Lane l owns channels [8l, 8l+8):
// 8 independent scattered loads per tensor (deep MLP, same inherent line
// traffic), shfl_xor butterfly reductions (no LDS, no barriers — replaces
// 3 x 8-level LDS trees), perfectly coalesced 16B s16x8 hi/lo stores.
// ---------------------------------------------------------------------------
__global__ __launch_bounds__(64) void k_gather(
    const float* __restrict__ fs, const float* __restrict__ ft,
    const int* __restrict__ idx_final, unsigned short* __restrict__ A2,
    float* __restrict__ out_logits) {
  int n = blockIdx.x;
  int p = idx_final[n];
  int b = p >> 12;
  int hw = p & (HW - 1);
  const float* fsb = fs + (size_t)b * C_DIM * HW + hw;
  const float* ftb = ft + (size_t)b * C_DIM * HW + hw;
  int lane = threadIdx.x;

  float s[8], t[8];
#pragma unroll
  for (int j = 0; j < 8; ++j) {
    int c = lane * 8 + j;
    s[j] = fsb[(size_t)c * HW];
    t[j] = ftb[(size_t)c * HW];
  }

  float ss = 0.f, tt = 0.f;
#pragma unroll
  for (int j = 0; j < 8; ++j) { ss += s[j] * s[j]; tt += t[j] * t[j]; }
#pragma unroll
  for (int m = 1; m < 64; m <<= 1) {
    ss += __shfl_xor(ss, m);
    tt += __shfl_xor(tt, m);
  }
  float ns = fmaxf(sqrtf(ss), 1e-12f);
  float nt = fmaxf(sqrtf(tt), 1e-12f);

  float st = 0.f;
  s16x8 vhi, vlo;
#pragma unroll
  for (int j = 0; j < 8; ++j) {
    float a = s[j] / ns;
    float bb = t[j] / nt;
    st += a * bb;
    unsigned short h = f2bf(a);
    vhi[j] = (short)h;
    vlo[j] = (short)f2bf(a - bf2f(h));
  }
  unsigned short* row = A2 + (size_t)n * KH;
  *(s16x8*)(row + lane * 8)       = vhi;
  *(s16x8*)(row + 512 + lane * 8) = vlo;

#pragma unroll
  for (int m = 1; m < 64; m <<= 1) st += __shfl_xor(st, m);
  if (lane == 0)
    out_logits[(size_t)n * L_ROW] = st * (1.0f / 0.07f);
}

// ---------------------------------------------------------------------------
// K5: l_neg via bf16-split MFMA GEMM, K'=1536. 64x64 tile = 768 blocks =
// 3/CU (verified R7: -barrier exposure vs 128x128). Mask fused in epilogue.
// ---------------------------------------------------------------------------
__global__ __launch_bounds__(256) void k_gemm(
    const unsigned short* __restrict__ A2,   // [1024][1024] {hi|lo}
    const unsigned short* __restrict__ B2,   // [3072][1024] {hi|lo} (B^T)
    const int* __restrict__ labels,
    const int* __restrict__ qlab,
    float* __restrict__ out) {
  __shared__ unsigned short sAB[8192];       // A: [0,4096) B: [4096,8192) u16
  int tid  = threadIdx.x;
  int lane = tid & 63;
  int wave = tid >> 6;
  int wm = wave >> 1, wn = wave & 1;         // 2x2 waves -> 32x32 each
  int bm = blockIdx.x * 64;                  // 16 m-tiles
  int bn = blockIdx.y * 64;                  // 48 n-tiles

  int r0 = tid >> 3;                         // rows r0, r0+32
  int g0 = tid & 7;                          // col8 group
  int slot0 = ((g0 ^ (r0 & 7)) << 3);

  f32x4 acc[2][2] = {};
  s16x8 ra[2], rb[2];

  const int NSTEP = KP / 64;                 // 24
  {
    ra[0] = *(const s16x8*)(A2 + (size_t)(bm + r0)      * KH + g0 * 8);
    ra[1] = *(const s16x8*)(A2 + (size_t)(bm + r0 + 32) * KH + g0 * 8);
    rb[0] = *(const s16x8*)(B2 + (size_t)(bn + r0)      * KH + g0 * 8);
    rb[1] = *(const s16x8*)(B2 + (size_t)(bn + r0 + 32) * KH + g0 * 8);
    *(s16x8*)&sAB[r0 * 64 + slot0]               = ra[0];
    *(s16x8*)&sAB[(r0 + 32) * 64 + slot0]        = ra[1];
    *(s16x8*)&sAB[4096 + r0 * 64 + slot0]        = rb[0];
    *(s16x8*)&sAB[4096 + (r0 + 32) * 64 + slot0] = rb[1];
  }
  __syncthreads();

  for (int s = 0; s < NSTEP; ++s) {
    if (s + 1 < NSTEP) {                     // T14: issue next loads early
      int kp = (s + 1) * 64;
      int sA = (kp < 512) ? kp : kp - 512;   // [Ahi;Ahi;Alo]
      int sB = (kp < 1024) ? kp : kp - 1024; // [Bhi;Blo;Bhi]
      ra[0] = *(const s16x8*)(A2 + (size_t)(bm + r0)      * KH + sA + g0 * 8);
      ra[1] = *(const s16x8*)(A2 + (size_t)(bm + r0 + 32) * KH + sA + g0 * 8);
      rb[0] = *(const s16x8*)(B2 + (size_t)(bn + r0)      * KH + sB + g0 * 8);
      rb[1] = *(const s16x8*)(B2 + (size_t)(bn + r0 + 32) * KH + sB + g0 * 8);
    }
#pragma unroll
    for (int kk = 0; kk < 2; ++kk) {
      int g = kk * 4 + (lane >> 4);
      s16x8 af[2], bfr[2];
#pragma unroll
      for (int mi = 0; mi < 2; ++mi) {
        int rowL = wm * 32 + mi * 16 + (lane & 15);
        af[mi] = *(s16x8*)&sAB[rowL * 64 + ((g ^ (rowL & 7)) << 3)];
      }
#pragma unroll
      for (int ni = 0; ni < 2; ++ni) {
        int rowN = wn * 32 + ni * 16 + (lane & 15);
        bfr[ni] = *(s16x8*)&sAB[4096 + rowN * 64 + ((g ^ (rowN & 7)) << 3)];
      }
#pragma unroll
      for (int mi = 0; mi < 2; ++mi)
#pragma unroll
        for (int ni = 0; ni < 2; ++ni)
          acc[mi][ni] = __builtin_amdgcn_mfma_f32_16x16x32_bf16(
              af[mi], bfr[ni], acc[mi][ni], 0, 0, 0);
    }
    __syncthreads();
    if (s + 1 < NSTEP) {
      *(s16x8*)&sAB[r0 * 64 + slot0]               = ra[0];
      *(s16x8*)&sAB[(r0 + 32) * 64 + slot0]        = ra[1];
      *(s16x8*)&sAB[4096 + r0 * 64 + slot0]        = rb[0];
      *(s16x8*)&sAB[4096 + (r0 + 32) * 64 + slot0] = rb[1];
      __syncthreads();
    }
  }

  // epilogue: stage labels in now-free LDS; write logits + mask
  int* labsh = (int*)sAB;                    // [0:64)=row labels [64:128)=qlab
  if (tid < 64)            labsh[tid] = labels[bm + tid];
  else if (tid < 128)      labsh[tid] = qlab[bn + (tid - 64)];
  __syncthreads();

  float* out_mask = out + (size_t)N_SAMP * L_ROW;
  const float sc = 1.0f / 0.07f;
#pragma unroll
  for (int mi = 0; mi < 2; ++mi) {
#pragma unroll
    for (int ni = 0; ni < 2; ++ni) {
#pragma unroll
      for (int j = 0; j < 4; ++j) {
        int rl = wm * 32 + mi * 16 + ((lane >> 4) << 2) + j;
        int cl = wn * 32 + ni * 16 + (lane & 15);
        int row = bm + rl, col = bn + cl;
        out[(size_t)row * L_ROW + 1 + col] = acc[mi][ni][j] * sc;
        out_mask[(size_t)row * K_Q + col] =
            (labsh[rl] == labsh[64 + cl]) ? 1.0f : 0.0f;
      }
    }
  }
}

// ---------------------------------------------------------------------------
// Launch — 6 dispatches. A2/B2 in ws (ws_size = 256 MiB, verified R6).
// ---------------------------------------------------------------------------
extern "C" void kernel_launch(void* const* d_in, const int* in_sizes, int n_in,
                              void* d_out, int out_size, void* d_ws, size_t ws_size,
                              hipStream_t stream) {
  const float* fs     = (const float*)d_in[1];
  const float* ft     = (const float*)d_in[2];
  const int*   target = (const int*)d_in[3];
  const float* queue  = (const float*)d_in[4];
  const int*   qlab   = (const int*)d_in[5];
  float* out = (float*)d_out;

  // ws layout (~10.3 MB of the 256 MiB)
  char* ws = (char*)d_ws;
  int* cnt   = (int*)(ws + 0);
  int* samp  = (int*)(ws + 4096);
  int* idxf  = (int*)(ws + 8192);
  int* labs  = (int*)(ws + 12288);
  int* lists = (int*)(ws + 16384);                          // 512 KB
  unsigned short* A2 = (unsigned short*)(ws + (1u << 20));  // 2 MB @ 1 MiB
  unsigned short* B2 = (unsigned short*)(ws + (4u << 20));  // 6.29 MB @ 4 MiB

  // host-side RNG key derivation (partitionable threefry — verified R1)
  uint32_t ck[5][2];
  for (int i = 0; i < 5; ++i)
    tf2x32(0u, 42u, 0u, (uint32_t)i, ck[i][0], ck[i][1]);
  uint32_t sk0, sk1;
  tf2x32(ck[4][0], ck[4][1], 0u, 1u, sk0, sk1);

  float* out_labels = out + (size_t)N_SAMP * L_ROW + (size_t)N_SAMP * K_Q;

  k_convq<<<dim3(K_Q / 64, C_DIM / 64), 256, 0, stream>>>(queue, B2, cnt);
  k_compact<<<N_PIX / 256, 256, 0, stream>>>(target, cnt, lists);
  k_sample<<<dim3(NQ, NCLS), 256, 0, stream>>>(
      cnt, lists, samp,
      ck[0][0], ck[0][1], ck[1][0], ck[1][1],
      ck[2][0], ck[2][1], ck[3][0], ck[3][1]);
  k_perm<<<16, 64, 0, stream>>>(samp, idxf, labs, out_labels, sk0, sk1);
  k_gather<<<N_SAMP, 64, 0, stream>>>(fs, ft, idxf, A2, out);
  k_gemm<<<dim3(N_SAMP / 64, K_Q / 64), 256, 0, stream>>>(
      A2, B2, labs, qlab, out);
}